// Round 5
// baseline (1073.120 us; speedup 1.0000x reference)
//
#include <hip/hip_runtime.h>

#define F 3
#define V 512
#define D 8192
#define B 64
#define ITERS 10
#define DW 256  // u32 words per D-row (D/32)
#define NBLK 192

typedef __bf16 bf16_t;
typedef __bf16 bf16x8 __attribute__((ext_vector_type(8)));
typedef float f32x4 __attribute__((ext_vector_type(4)));
typedef unsigned int u32;
typedef unsigned short u16;
typedef u16 u16x8 __attribute__((ext_vector_type(8)));
typedef unsigned long long u64;

// ---------------------------------------------------------------------------
// Values are in {0,+1,-1}. sign bit s=1 <=> v<0; zero bit z=1 <=> v==0.
// dot(A,c) = nzc - 2*popc((As ^ cs) & ~Az)  (exact integers).
//
// Coherence design (r4 post-mortem): NO __threadfence anywhere in the main
// loop — agent fences emit full L2 invalidates (buffer_inv), which forced a
// ~13 MB refetch per iteration (130 MB total, the entire runtime). Instead,
// all cross-phase MUTABLE data (sim, est planes, flags) uses agent-scope
// RELAXED atomics (performed at the coherent point, cross-XCD coherent by
// construction); read-only operands (Cbits, CbTb, in_bits) use plain cached
// loads and stay L2-resident (~3.2 MB/XCD < 4 MB).
// ---------------------------------------------------------------------------

__device__ inline int aload(const int* p) {
  return __hip_atomic_load((int*)p, __ATOMIC_RELAXED, __HIP_MEMORY_SCOPE_AGENT);
}
__device__ inline u32 aloadu(const u32* p) {
  return __hip_atomic_load((u32*)p, __ATOMIC_RELAXED, __HIP_MEMORY_SCOPE_AGENT);
}
__device__ inline void astore(int* p, int v) {
  __hip_atomic_store(p, v, __ATOMIC_RELAXED, __HIP_MEMORY_SCOPE_AGENT);
}
__device__ inline void astoreu(u32* p, u32 v) {
  __hip_atomic_store(p, v, __ATOMIC_RELAXED, __HIP_MEMORY_SCOPE_AGENT);
}

// ---------------------------------------------------------------------------
// init: codebook bit-pack both ways + flag zeroing.
// Cbits[f][wc][v][j]: d-bit-packed (for sim phase, uint4-tiled over d-words)
// CbTb[f][d][vw]:     v-bit-packed (for upd phase B-operand expansion)
// ---------------------------------------------------------------------------
__global__ __launch_bounds__(256) void k_init_tr(const float* __restrict__ Csrc,
                                                 u32* __restrict__ Cbits,
                                                 u32* __restrict__ CbTb,
                                                 int* __restrict__ flags) {
  int f = blockIdx.z, vt = blockIdx.y, dt = blockIdx.x;
  __shared__ bf16_t tile[64 * 65];
  int t = threadIdx.x;
  int lane = t & 63;
  int v0 = vt * 64, d0 = dt * 64;
  if (f == 0 && vt == 0 && dt == 0 && t < 32) flags[t] = 0;
#pragma unroll
  for (int p = 0; p < 16; ++p) {
    int q = t + 256 * p;
    int i = q >> 6, j = q & 63;  // j == lane, i uniform per wave
    float x = Csrc[((long)(f * V + v0 + i)) * D + d0 + j];
    tile[i * 65 + j] = (bf16_t)x;
    u64 bal = __ballot(x < 0.f);  // bit l <-> d = d0 + l
    if (lane == 0) {
      int v = v0 + i;
      uint2 wp;
      wp.x = (u32)(bal & 0xffffffffull);
      wp.y = (u32)(bal >> 32);
      *(uint2*)&Cbits[(((f * 64 + (dt >> 1)) * 512) + v) * 4 + (dt & 1) * 2] = wp;
    }
  }
  __syncthreads();
#pragma unroll
  for (int p = 0; p < 16; ++p) {
    int q = t + 256 * p;
    int jj = q >> 6, ii = q & 63;  // jj uniform per wave (=4p+w), ii == lane == v-offset
    float xv = (float)tile[ii * 65 + jj];
    u64 bal = __ballot(xv < 0.f);  // bit l <-> v = v0 + l
    if (lane == 0) {
      int d = d0 + jj;
      uint2 wp;
      wp.x = (u32)(bal & 0xffffffffull);
      wp.y = (u32)(bal >> 32);
      *(uint2*)&CbTb[((long)f * D + d) * 16 + vt * 2] = wp;
    }
  }
}

// ---------------------------------------------------------------------------
// init (bit-pack inputs + init estimates; raise has_zero if any est zero)
// ---------------------------------------------------------------------------
__global__ void k_init_pack(const float* __restrict__ inputs, const float* __restrict__ ie,
                            u32* __restrict__ in_bits, u32* __restrict__ es0,
                            u32* __restrict__ ez0, int* __restrict__ flags) {
  int tid = blockIdx.x * blockDim.x + threadIdx.x;
  int lane = tid & 63;
  int gw = tid >> 6;
  int NW = (gridDim.x * blockDim.x) >> 6;
  const int IN_W = B * (D / 64);       // 8192 chunks
  const int EST_W = B * F * (D / 64);  // 24576
  for (int c = gw; c < IN_W + EST_W; c += NW) {
    if (c < IN_W) {
      int b = c >> 7, dc = c & 127;
      float x = inputs[(long)b * D + dc * 64 + lane];
      u64 bal = __ballot(x < 0.f);
      if (lane == 0) {
        in_bits[b * DW + dc * 2] = (u32)(bal & 0xffffffffull);
        in_bits[b * DW + dc * 2 + 1] = (u32)(bal >> 32);
      }
    } else {
      int cc = c - IN_W;
      int bf = cc >> 7, dc = cc & 127;  // bf = b*F + f
      float x = ie[(long)bf * D + dc * 64 + lane];
      u64 bs = __ballot(x < 0.f);
      u64 bz = __ballot(x == 0.f);
      if (lane == 0) {
        es0[bf * DW + dc * 2] = (u32)(bs & 0xffffffffull);
        es0[bf * DW + dc * 2 + 1] = (u32)(bs >> 32);
        ez0[bf * DW + dc * 2] = (u32)(bz & 0xffffffffull);
        ez0[bf * DW + dc * 2 + 1] = (u32)(bz >> 32);
        if (bz) atomicOr(&flags[16], 1);
      }
    }
  }
}

// ---------------------------------------------------------------------------
// software grid barrier: sense-reversing generation counter, agent scope.
// NO fences: release semantics of the acq_rel fetch_add waits vmcnt(0), so
// each block's prior coherent-point (atomic) data stores are complete before
// its arrival is visible; consumers' post-barrier atomic loads read the
// coherent point directly. Poll is RELAXED (no per-poll cache invalidate).
// Safe: 192 blocks <= 256 CUs, 45KB LDS/block -> all blocks co-resident.
// ---------------------------------------------------------------------------
__device__ inline void grid_sync(int* counter, int* gen) {
  __syncthreads();
  if (threadIdx.x == 0) {
    int g = __hip_atomic_load(gen, __ATOMIC_RELAXED, __HIP_MEMORY_SCOPE_AGENT);
    int a = __hip_atomic_fetch_add(counter, 1, __ATOMIC_ACQ_REL, __HIP_MEMORY_SCOPE_AGENT);
    if (a == NBLK - 1) {
      __hip_atomic_store(counter, 0, __ATOMIC_RELAXED, __HIP_MEMORY_SCOPE_AGENT);
      __hip_atomic_store(gen, g + 1, __ATOMIC_RELEASE, __HIP_MEMORY_SCOPE_AGENT);
    } else {
      while (__hip_atomic_load(gen, __ATOMIC_RELAXED, __HIP_MEMORY_SCOPE_AGENT) == g)
        __builtin_amdgcn_s_sleep(2);
    }
  }
  __syncthreads();
}

// ---------------------------------------------------------------------------
// fused iteration kernel: per iter, sim phase (bit popcount, 768 waves)
// -> grid_sync -> upd phase (exact 256h+l bf16 MFMA, B expanded from bits)
// -> grid_sync -> uniform convergence check. Tail: final projection + argmax.
// grid 192 x 256. flags[0..9]=anydiff, [16]=has_zero, [24]=bar cnt, [25]=gen.
// ---------------------------------------------------------------------------
__global__ __launch_bounds__(256) void k_fused(
    const u32* __restrict__ Cbits, const u32* __restrict__ in_bits,
    u32* __restrict__ es0, u32* __restrict__ ez0,
    u32* __restrict__ es1, u32* __restrict__ ez1,
    const u32* __restrict__ CbTb, int* __restrict__ sim,
    int* __restrict__ flags, int* __restrict__ out) {
  __shared__ __attribute__((aligned(16))) bf16_t lAh[64 * 88];   // [b][v]
  __shared__ __attribute__((aligned(16))) bf16_t lAl[64 * 88];   // [b][v]
  __shared__ __attribute__((aligned(16))) bf16_t lB[128 * 88];   // [d][v]
  __shared__ int sh_hz, sh_conv;

  int* bar_cnt = flags + 24;
  int* bar_gen = flags + 25;

  const int bid = blockIdx.x;
  const int t = threadIdx.x, lane = t & 63, w = t >> 6;
  const int lm = lane & 15, quad = lane >> 4;
  // sim-phase wave task: 768 waves
  const int gw = bid * 4 + w;
  const int vg = gw & 7, bp = (gw >> 3) & 31, fs = gw >> 8;
  const int b0 = bp * 2;
  // upd-phase block task: 192 blocks
  const int du = (bid & 63) * 128, fu = bid >> 6;

  int parity = 0;        // current est plane: 0 -> es0/ez0
  int done_iter = ITERS;

  if (t == 0) sh_hz = aload(&flags[16]);
  __syncthreads();

  auto sim_phase = [&](bool is_final, int hz) {
    const u32* es = parity ? es1 : es0;
    const u32* ez = parity ? ez1 : ez0;
    u32 As0[4], As1[4], Az0[4], Az1[4];
    if (is_final) {
      const int i0 = (b0 * F + fs) * DW, i1 = ((b0 + 1) * F + fs) * DW;
#pragma unroll
      for (int r = 0; r < 4; ++r) {
        int o = r * 64 + lane;
        As0[r] = aloadu(es + i0 + o);
        As1[r] = aloadu(es + i1 + o);
      }
      if (hz) {
#pragma unroll
        for (int r = 0; r < 4; ++r) {
          int o = r * 64 + lane;
          Az0[r] = ~aloadu(ez + i0 + o);
          Az1[r] = ~aloadu(ez + i1 + o);
        }
      }
    } else {
      const int f1 = (fs + 1) % 3, f2 = (fs + 2) % 3;
      const int a0 = (b0 * F + f1) * DW, a1 = (b0 * F + f2) * DW;
      const int c0 = ((b0 + 1) * F + f1) * DW, c1 = ((b0 + 1) * F + f2) * DW;
      const int n0 = b0 * DW, n1 = (b0 + 1) * DW;
#pragma unroll
      for (int r = 0; r < 4; ++r) {
        int o = r * 64 + lane;
        As0[r] = in_bits[n0 + o] ^ aloadu(es + a0 + o) ^ aloadu(es + a1 + o);
        As1[r] = in_bits[n1 + o] ^ aloadu(es + c0 + o) ^ aloadu(es + c1 + o);
      }
      if (hz) {
#pragma unroll
        for (int r = 0; r < 4; ++r) {
          int o = r * 64 + lane;
          Az0[r] = ~(aloadu(ez + a0 + o) | aloadu(ez + a1 + o));
          Az1[r] = ~(aloadu(ez + c0 + o) | aloadu(ez + c1 + o));
        }
      }
    }

    int nzc0 = D, nzc1 = D;
    if (hz) {
      int p0 = 0, p1 = 0;
#pragma unroll
      for (int r = 0; r < 4; ++r) {
        p0 += __popc(Az0[r]);
        p1 += __popc(Az1[r]);
      }
      for (int off = 32; off; off >>= 1) {
        p0 += __shfl_xor(p0, off, 64);
        p1 += __shfl_xor(p1, off, 64);
      }
      nzc0 = p0;
      nzc1 = p1;
    }

    int acc0 = 0, acc1 = 0;
    const uint4* Cp = (const uint4*)Cbits + ((long)fs * 64) * 512 + vg * 64 + lane;
    if (!hz) {
#pragma unroll
      for (int r = 0; r < 4; ++r) {
#pragma unroll
        for (int i = 0; i < 16; ++i) {
          uint4 c = Cp[(r * 16 + i) * 512];
          const int k = i * 4;
          u32 a;
          a = (u32)__builtin_amdgcn_readlane((int)As0[r], k + 0); acc0 += __popc(c.x ^ a);
          a = (u32)__builtin_amdgcn_readlane((int)As0[r], k + 1); acc0 += __popc(c.y ^ a);
          a = (u32)__builtin_amdgcn_readlane((int)As0[r], k + 2); acc0 += __popc(c.z ^ a);
          a = (u32)__builtin_amdgcn_readlane((int)As0[r], k + 3); acc0 += __popc(c.w ^ a);
          a = (u32)__builtin_amdgcn_readlane((int)As1[r], k + 0); acc1 += __popc(c.x ^ a);
          a = (u32)__builtin_amdgcn_readlane((int)As1[r], k + 1); acc1 += __popc(c.y ^ a);
          a = (u32)__builtin_amdgcn_readlane((int)As1[r], k + 2); acc1 += __popc(c.z ^ a);
          a = (u32)__builtin_amdgcn_readlane((int)As1[r], k + 3); acc1 += __popc(c.w ^ a);
        }
      }
    } else {
#pragma unroll
      for (int r = 0; r < 4; ++r) {
#pragma unroll
        for (int i = 0; i < 16; ++i) {
          uint4 c = Cp[(r * 16 + i) * 512];
          const int k = i * 4;
          u32 a, z;
          a = (u32)__builtin_amdgcn_readlane((int)As0[r], k + 0);
          z = (u32)__builtin_amdgcn_readlane((int)Az0[r], k + 0); acc0 += __popc((c.x ^ a) & z);
          a = (u32)__builtin_amdgcn_readlane((int)As0[r], k + 1);
          z = (u32)__builtin_amdgcn_readlane((int)Az0[r], k + 1); acc0 += __popc((c.y ^ a) & z);
          a = (u32)__builtin_amdgcn_readlane((int)As0[r], k + 2);
          z = (u32)__builtin_amdgcn_readlane((int)Az0[r], k + 2); acc0 += __popc((c.z ^ a) & z);
          a = (u32)__builtin_amdgcn_readlane((int)As0[r], k + 3);
          z = (u32)__builtin_amdgcn_readlane((int)Az0[r], k + 3); acc0 += __popc((c.w ^ a) & z);
          a = (u32)__builtin_amdgcn_readlane((int)As1[r], k + 0);
          z = (u32)__builtin_amdgcn_readlane((int)Az1[r], k + 0); acc1 += __popc((c.x ^ a) & z);
          a = (u32)__builtin_amdgcn_readlane((int)As1[r], k + 1);
          z = (u32)__builtin_amdgcn_readlane((int)Az1[r], k + 1); acc1 += __popc((c.y ^ a) & z);
          a = (u32)__builtin_amdgcn_readlane((int)As1[r], k + 2);
          z = (u32)__builtin_amdgcn_readlane((int)Az1[r], k + 2); acc1 += __popc((c.z ^ a) & z);
          a = (u32)__builtin_amdgcn_readlane((int)As1[r], k + 3);
          z = (u32)__builtin_amdgcn_readlane((int)Az1[r], k + 3); acc1 += __popc((c.w ^ a) & z);
        }
      }
    }
    const int v = vg * 64 + lane;
    astore(&sim[(fs * B + b0) * V + v], nzc0 - 2 * acc0);
    astore(&sim[(fs * B + b0 + 1) * V + v], nzc1 - 2 * acc1);
  };

  auto upd_phase = [&](int j) {
    const u32* esIn = parity ? es1 : es0;
    const u32* ezIn = parity ? ez1 : ez0;
    u32* esOut = parity ? es0 : es1;
    u32* ezOut = parity ? ez0 : ez1;
    const int* simf = sim + fu * (B * V);

    f32x4 zero = {0.f, 0.f, 0.f, 0.f};
    f32x4 accH[4][2], accL[4][2];
#pragma unroll
    for (int mt = 0; mt < 4; ++mt)
#pragma unroll
      for (int nt = 0; nt < 2; ++nt) { accH[mt][nt] = zero; accL[mt][nt] = zero; }

    for (int c = 0; c < 8; ++c) {
      const int vb = c * 64;
      __syncthreads();
#pragma unroll
      for (int p = 0; p < 2; ++p) {
        int q = t + 256 * p;
        int b = q >> 3, vv = (q & 7) * 8;
        const int* sp = simf + b * V + vb + vv;
#pragma unroll
        for (int i = 0; i < 8; ++i) {
          int si = aload(sp + i);
          lAh[b * 88 + vv + i] = (bf16_t)(float)(si >> 8);
          lAl[b * 88 + vv + i] = (bf16_t)(float)(si & 255);
        }
      }
      // B-operand: expand +-1 bf16 from v-bit-packed codebook plane (L2-hot)
#pragma unroll
      for (int p = 0; p < 4; ++p) {
        int q = t + 256 * p;
        int r = q >> 3, vv = (q & 7) * 8;
        u32 bits = CbTb[((long)fu * D + du + r) * 16 + ((vb + vv) >> 5)];
        int sh = (vb + vv) & 31;
        u16x8 o;
#pragma unroll
        for (int i = 0; i < 8; ++i)
          o[i] = (u16)(0x3F80u | (((bits >> (sh + i)) & 1u) << 15));  // +-1.0 bf16
        *(u16x8*)&lB[r * 88 + vv] = o;
      }
      __syncthreads();
#pragma unroll
      for (int ks2 = 0; ks2 < 2; ++ks2) {
        const int kb = ks2 * 32 + quad * 8;
        bf16x8 bf0 = *(const bf16x8*)&lB[(w * 32 + lm) * 88 + kb];
        bf16x8 bf1 = *(const bf16x8*)&lB[(w * 32 + 16 + lm) * 88 + kb];
#pragma unroll
        for (int mt = 0; mt < 4; ++mt) {
          bf16x8 ah = *(const bf16x8*)&lAh[(mt * 16 + lm) * 88 + kb];
          bf16x8 al = *(const bf16x8*)&lAl[(mt * 16 + lm) * 88 + kb];
          accH[mt][0] = __builtin_amdgcn_mfma_f32_16x16x32_bf16(ah, bf0, accH[mt][0], 0, 0, 0);
          accH[mt][1] = __builtin_amdgcn_mfma_f32_16x16x32_bf16(ah, bf1, accH[mt][1], 0, 0, 0);
          accL[mt][0] = __builtin_amdgcn_mfma_f32_16x16x32_bf16(al, bf0, accL[mt][0], 0, 0, 0);
          accL[mt][1] = __builtin_amdgcn_mfma_f32_16x16x32_bf16(al, bf1, accL[mt][1], 0, 0, 0);
        }
      }
    }
    // epilogue: ballot-packed sign/zero words; warp w owns d-word W.
    const int W = (bid & 63) * 4 + w;
    bool anyd = false, zf = false;
#pragma unroll
    for (int mt = 0; mt < 4; ++mt)
#pragma unroll
      for (int r = 0; r < 4; ++r) {
        float v0 = 256.f * accH[mt][0][r] + accL[mt][0][r];
        float v1 = 256.f * accH[mt][1][r] + accL[mt][1][r];
        u64 s0 = __ballot(v0 < 0.f);
        u64 s1 = __ballot(v1 < 0.f);
        u64 z0 = __ballot(v0 == 0.f);
        u64 z1 = __ballot(v1 == 0.f);
        zf |= ((z0 | z1) != 0ull);
        if (lm == 0) {
          u32 ws = (u32)((s0 >> (quad * 16)) & 0xffffull) |
                   (((u32)((s1 >> (quad * 16)) & 0xffffull)) << 16);
          u32 wz = (u32)((z0 >> (quad * 16)) & 0xffffull) |
                   (((u32)((z1 >> (quad * 16)) & 0xffffull)) << 16);
          int b = mt * 16 + quad * 4 + r;
          int idx = (b * F + fu) * DW + W;
          anyd |= (aloadu(esIn + idx) != ws) || (aloadu(ezIn + idx) != wz);
          astoreu(esOut + idx, ws);
          astoreu(ezOut + idx, wz);
        }
      }
    if (__any(anyd) && lane == 0) atomicOr(&flags[j], 1);
    if (zf && lane == 0) atomicOr(&flags[16], 1);
  };

  for (int j = 0; j < ITERS; ++j) {
    sim_phase(false, sh_hz);
    grid_sync(bar_cnt, bar_gen);
    upd_phase(j);
    grid_sync(bar_cnt, bar_gen);
    if (t == 0) {
      sh_conv = aload(&flags[j]);
      sh_hz = aload(&flags[16]);
    }
    __syncthreads();
    parity ^= 1;
    if (sh_conv == 0) { done_iter = j; break; }  // uniform across grid
  }

  sim_phase(true, sh_hz);  // final projection with newest est
  grid_sync(bar_cnt, bar_gen);

  // argmax phase: block bid -> (b,f), first wave only
  if (t < 64) {
    int b = bid / F, f = bid % F;
    const int* row = sim + (f * B + b) * V;
    int best = -2147483647;
    int bidx = 0;
#pragma unroll
    for (int i = 0; i < V / 64; ++i) {
      int v = lane + 64 * i;  // ascending within lane -> strict > keeps first max
      int x = aload(row + v);
      if (x > best) { best = x; bidx = v; }
    }
    for (int off = 32; off; off >>= 1) {
      int ov = __shfl_down(best, off, 64);
      int oi = __shfl_down(bidx, off, 64);
      if (ov > best || (ov == best && oi < bidx)) { best = ov; bidx = oi; }
    }
    if (lane == 0) out[b * F + f] = bidx;
  }
  if (bid == 0 && t == 0) {
    int cnt = (done_iter < ITERS) ? (done_iter + 1) : ITERS;
    out[B * F] = cnt - 1;
  }
}

// ---------------------------------------------------------------------------
extern "C" void kernel_launch(void* const* d_in, const int* in_sizes, int n_in,
                              void* d_out, int out_size, void* d_ws, size_t ws_size,
                              hipStream_t stream) {
  const float* inputs    = (const float*)d_in[0];  // (B, D)
  const float* init_est  = (const float*)d_in[1];  // (B, F, D)
  const float* codebooks = (const float*)d_in[2];  // (F, V, D)

  char* w = (char*)d_ws;
  size_t o = 0;
  auto alloc = [&](size_t bytes) -> void* {
    void* p = w + o;
    o = (o + bytes + 255) & ~(size_t)255;
    return p;
  };
  u32* Cbits   = (u32*)alloc((size_t)F * 64 * 512 * 4 * 4);  // d-bit-packed, sim layout
  u32* CbTb    = (u32*)alloc((size_t)F * D * 16 * 4);        // v-bit-packed, upd layout
  u32* in_bits = (u32*)alloc((size_t)B * DW * 4);
  u32* es0     = (u32*)alloc((size_t)B * F * DW * 4);
  u32* ez0     = (u32*)alloc((size_t)B * F * DW * 4);
  u32* es1     = (u32*)alloc((size_t)B * F * DW * 4);
  u32* ez1     = (u32*)alloc((size_t)B * F * DW * 4);
  int* sim     = (int*)alloc((size_t)F * B * V * 4);
  int* flags   = (int*)alloc(128);

  k_init_tr<<<dim3(128, 8, 3), 256, 0, stream>>>(codebooks, Cbits, CbTb, flags);
  k_init_pack<<<1024, 256, 0, stream>>>(inputs, init_est, in_bits, es0, ez0, flags);
  k_fused<<<NBLK, 256, 0, stream>>>(Cbits, in_bits, es0, ez0, es1, ez1, CbTb, sim,
                                    flags, (int*)d_out);
}

// Round 6
// 533.930 us; speedup vs baseline: 2.0099x; 2.0099x over previous
//
#include <hip/hip_runtime.h>

#define F 3
#define V 512
#define D 8192
#define B 64
#define ITERS 10
#define DW 256  // u32 words per D-row (D/32)

typedef __bf16 bf16_t;
typedef __bf16 bf16x8 __attribute__((ext_vector_type(8)));
typedef float f32x4 __attribute__((ext_vector_type(4)));
typedef unsigned int u32;
typedef unsigned short u16;
typedef u16 u16x8 __attribute__((ext_vector_type(8)));
typedef unsigned long long u64;

// ---------------------------------------------------------------------------
// Values are in {0,+1,-1}. sign bit s=1 <=> v<0; zero bit z=1 <=> v==0.
// dot(A,c) = nzc - 2*popc((As ^ cs) & ~Az)  (exact integers).
// Multi-launch design (r5 post-mortem): kernel-launch boundaries give free
// cross-XCD coherence -> plain cached vectorized loads everywhere. The fused
// single-kernel variants (r3-r5) were latency-bound at 3 waves/CU with
// coherent-point atomics; multi-launch + 512-thread blocks (8 waves/CU)
// hides latency instead.
// ---------------------------------------------------------------------------

// ---------------------------------------------------------------------------
// init: codebook bit-pack both ways + flag zeroing.
// Cbits[f][wc][v][j]: d-bit-packed (sim phase, uint4-tiled over d-words)
// CbTb[f][d][vw]:     v-bit-packed (upd phase B-operand LDS expansion)
// ---------------------------------------------------------------------------
__global__ __launch_bounds__(256) void k_init_tr(const float* __restrict__ Csrc,
                                                 u32* __restrict__ Cbits,
                                                 u32* __restrict__ CbTb,
                                                 int* __restrict__ flags) {
  int f = blockIdx.z, vt = blockIdx.y, dt = blockIdx.x;
  __shared__ bf16_t tile[64 * 65];
  int t = threadIdx.x;
  int lane = t & 63;
  int v0 = vt * 64, d0 = dt * 64;
  if (f == 0 && vt == 0 && dt == 0 && t < 32) flags[t] = 0;
#pragma unroll
  for (int p = 0; p < 16; ++p) {
    int q = t + 256 * p;
    int i = q >> 6, j = q & 63;  // j == lane, i uniform per wave
    float x = Csrc[((long)(f * V + v0 + i)) * D + d0 + j];
    tile[i * 65 + j] = (bf16_t)x;
    u64 bal = __ballot(x < 0.f);  // bit l <-> d = d0 + l
    if (lane == 0) {
      int v = v0 + i;
      uint2 wp;
      wp.x = (u32)(bal & 0xffffffffull);
      wp.y = (u32)(bal >> 32);
      *(uint2*)&Cbits[(((f * 64 + (dt >> 1)) * 512) + v) * 4 + (dt & 1) * 2] = wp;
    }
  }
  __syncthreads();
#pragma unroll
  for (int p = 0; p < 16; ++p) {
    int q = t + 256 * p;
    int jj = q >> 6, ii = q & 63;  // jj uniform per wave, ii == lane == v-offset
    float xv = (float)tile[ii * 65 + jj];
    u64 bal = __ballot(xv < 0.f);  // bit l <-> v = v0 + l
    if (lane == 0) {
      int d = d0 + jj;
      uint2 wp;
      wp.x = (u32)(bal & 0xffffffffull);
      wp.y = (u32)(bal >> 32);
      *(uint2*)&CbTb[((long)f * D + d) * 16 + vt * 2] = wp;
    }
  }
}

// ---------------------------------------------------------------------------
// init (bit-pack inputs + init estimates; raise has_zero if any est zero)
// ---------------------------------------------------------------------------
__global__ void k_init_pack(const float* __restrict__ inputs, const float* __restrict__ ie,
                            u32* __restrict__ in_bits, u32* __restrict__ es0,
                            u32* __restrict__ ez0, int* __restrict__ flags) {
  int tid = blockIdx.x * blockDim.x + threadIdx.x;
  int lane = tid & 63;
  int gw = tid >> 6;
  int NW = (gridDim.x * blockDim.x) >> 6;
  const int IN_W = B * (D / 64);       // 8192 chunks
  const int EST_W = B * F * (D / 64);  // 24576
  for (int c = gw; c < IN_W + EST_W; c += NW) {
    if (c < IN_W) {
      int b = c >> 7, dc = c & 127;
      float x = inputs[(long)b * D + dc * 64 + lane];
      u64 bal = __ballot(x < 0.f);
      if (lane == 0) {
        in_bits[b * DW + dc * 2] = (u32)(bal & 0xffffffffull);
        in_bits[b * DW + dc * 2 + 1] = (u32)(bal >> 32);
      }
    } else {
      int cc = c - IN_W;
      int bf = cc >> 7, dc = cc & 127;  // bf = b*F + f
      float x = ie[(long)bf * D + dc * 64 + lane];
      u64 bs = __ballot(x < 0.f);
      u64 bz = __ballot(x == 0.f);
      if (lane == 0) {
        es0[bf * DW + dc * 2] = (u32)(bs & 0xffffffffull);
        es0[bf * DW + dc * 2 + 1] = (u32)(bs >> 32);
        ez0[bf * DW + dc * 2] = (u32)(bz & 0xffffffffull);
        ez0[bf * DW + dc * 2 + 1] = (u32)(bz >> 32);
        if (bz) atomicOr(&flags[16], 1);
      }
    }
  }
}

// ---------------------------------------------------------------------------
// kernel A (binary): sim[f][b][v] = dot over D. One wave per (f, b, vg):
// 1536 waves = 192 blocks x 512 threads (8 waves/CU on active CUs).
// Plain cached loads (launch-boundary coherence). Each sim element written
// exactly once, no atomics, no LDS, no zero-fill needed.
// ---------------------------------------------------------------------------
__global__ __launch_bounds__(512) void k_sim(const u32* __restrict__ Cbits,
                                             const u32* __restrict__ in_bits,
                                             const u32* __restrict__ es0,
                                             const u32* __restrict__ ez0,
                                             const u32* __restrict__ es1,
                                             const u32* __restrict__ ez1,
                                             int* __restrict__ sim,
                                             const int* __restrict__ flags, int iter) {
  const int t = threadIdx.x, lane = t & 63, w = t >> 6;
  const int gw = blockIdx.x * 8 + w;  // 0..1535
  const int vg = gw & 7, b = (gw >> 3) & 63, fs = gw >> 9;
  const bool is_final = (iter >= ITERS);
  const u32 *es, *ez;
  if (is_final) {
    int first0 = ITERS;
    for (int i = 0; i < ITERS; ++i)
      if (flags[i] == 0) { first0 = i; break; }
    int par = (first0 < ITERS) ? ((first0 + 1) & 1) : 0;
    es = par ? es1 : es0;
    ez = par ? ez1 : ez0;
  } else {
    for (int i = 0; i < iter; ++i)
      if (flags[i] == 0) return;  // converged earlier: uniform exit
    es = (iter & 1) ? es1 : es0;
    ez = (iter & 1) ? ez1 : ez0;
  }
  const int hz = flags[16];

  u32 As[4], Az[4];
  if (is_final) {
    const int i0 = (b * F + fs) * DW;
#pragma unroll
    for (int r = 0; r < 4; ++r) As[r] = es[i0 + r * 64 + lane];
    if (hz) {
#pragma unroll
      for (int r = 0; r < 4; ++r) Az[r] = ~ez[i0 + r * 64 + lane];
    }
  } else {
    const int f1 = (fs + 1) % 3, f2 = (fs + 2) % 3;
    const int a0 = (b * F + f1) * DW, a1 = (b * F + f2) * DW;
    const int n0 = b * DW;
#pragma unroll
    for (int r = 0; r < 4; ++r) {
      int o = r * 64 + lane;
      As[r] = in_bits[n0 + o] ^ es[a0 + o] ^ es[a1 + o];
    }
    if (hz) {
#pragma unroll
      for (int r = 0; r < 4; ++r) {
        int o = r * 64 + lane;
        Az[r] = ~(ez[a0 + o] | ez[a1 + o]);
      }
    }
  }

  int nzc = D;
  if (hz) {
    int p0 = 0;
#pragma unroll
    for (int r = 0; r < 4; ++r) p0 += __popc(Az[r]);
    for (int off = 32; off; off >>= 1) p0 += __shfl_xor(p0, off, 64);
    nzc = p0;
  }

  int acc = 0;
  const uint4* Cp = (const uint4*)Cbits + ((long)fs * 64) * 512 + vg * 64 + lane;
  if (!hz) {
#pragma unroll
    for (int r = 0; r < 4; ++r) {
#pragma unroll
      for (int i = 0; i < 16; ++i) {
        uint4 c = Cp[(r * 16 + i) * 512];
        const int k = i * 4;
        u32 a;
        a = (u32)__builtin_amdgcn_readlane((int)As[r], k + 0); acc += __popc(c.x ^ a);
        a = (u32)__builtin_amdgcn_readlane((int)As[r], k + 1); acc += __popc(c.y ^ a);
        a = (u32)__builtin_amdgcn_readlane((int)As[r], k + 2); acc += __popc(c.z ^ a);
        a = (u32)__builtin_amdgcn_readlane((int)As[r], k + 3); acc += __popc(c.w ^ a);
      }
    }
  } else {
#pragma unroll
    for (int r = 0; r < 4; ++r) {
#pragma unroll
      for (int i = 0; i < 16; ++i) {
        uint4 c = Cp[(r * 16 + i) * 512];
        const int k = i * 4;
        u32 a, z;
        a = (u32)__builtin_amdgcn_readlane((int)As[r], k + 0);
        z = (u32)__builtin_amdgcn_readlane((int)Az[r], k + 0); acc += __popc((c.x ^ a) & z);
        a = (u32)__builtin_amdgcn_readlane((int)As[r], k + 1);
        z = (u32)__builtin_amdgcn_readlane((int)Az[r], k + 1); acc += __popc((c.y ^ a) & z);
        a = (u32)__builtin_amdgcn_readlane((int)As[r], k + 2);
        z = (u32)__builtin_amdgcn_readlane((int)Az[r], k + 2); acc += __popc((c.z ^ a) & z);
        a = (u32)__builtin_amdgcn_readlane((int)As[r], k + 3);
        z = (u32)__builtin_amdgcn_readlane((int)Az[r], k + 3); acc += __popc((c.w ^ a) & z);
      }
    }
  }
  sim[(fs * B + b) * V + vg * 64 + lane] = nzc - 2 * acc;
}

// ---------------------------------------------------------------------------
// kernel B: est' = sign(sim . C), exact 256*h + l bf16 MFMA split, B operand
// expanded from v-bit-packed CbTb in LDS. grid 192 x 512 (8 warps/block):
// warp w -> (wm = w>>2: b-half, wd = w&3: 32-d column). Ballot epilogue
// writes sign/zero bit planes; warp owns d-word W = dt*4 + wd.
// ---------------------------------------------------------------------------
__global__ __launch_bounds__(512) void k_upd(const int* __restrict__ sim,
                                             const u32* __restrict__ CbTb,
                                             u32* __restrict__ es0, u32* __restrict__ ez0,
                                             u32* __restrict__ es1, u32* __restrict__ ez1,
                                             int* __restrict__ flags, int iter) {
  const int fu = blockIdx.x >> 6;
  const int dt = blockIdx.x & 63, d0 = dt * 128;
  for (int i = 0; i < iter; ++i)
    if (flags[i] == 0) return;
  const u32* esIn = (iter & 1) ? es1 : es0;
  const u32* ezIn = (iter & 1) ? ez1 : ez0;
  u32* esOut = (iter & 1) ? es0 : es1;
  u32* ezOut = (iter & 1) ? ez0 : ez1;
  const int* simf = sim + fu * (B * V);

  __shared__ __attribute__((aligned(16))) bf16_t lAh[64 * 88];   // [b][v]
  __shared__ __attribute__((aligned(16))) bf16_t lAl[64 * 88];   // [b][v]
  __shared__ __attribute__((aligned(16))) bf16_t lB[128 * 88];   // [d][v]

  const int t = threadIdx.x;
  const int lane = t & 63, w = t >> 6;
  const int lm = lane & 15, quad = lane >> 4;
  const int wd = w & 3, wm = w >> 2;

  f32x4 zero = {0.f, 0.f, 0.f, 0.f};
  f32x4 accH[2][2], accL[2][2];
#pragma unroll
  for (int m = 0; m < 2; ++m)
#pragma unroll
    for (int nt = 0; nt < 2; ++nt) { accH[m][nt] = zero; accL[m][nt] = zero; }

  for (int c = 0; c < 8; ++c) {
    const int vb = c * 64;
    __syncthreads();
    // stage A: 64 b x 64 v ints -> h/l bf16 split (512 threads, 8 ints each)
    {
      int b8 = t >> 3, vv = (t & 7) * 8;
      const int* sp = simf + b8 * V + vb + vv;
      int4 sa = ((const int4*)sp)[0];
      int4 sb = ((const int4*)sp)[1];
      int si[8] = {sa.x, sa.y, sa.z, sa.w, sb.x, sb.y, sb.z, sb.w};
#pragma unroll
      for (int i = 0; i < 8; ++i) {
        lAh[b8 * 88 + vv + i] = (bf16_t)(float)(si[i] >> 8);
        lAl[b8 * 88 + vv + i] = (bf16_t)(float)(si[i] & 255);
      }
    }
    // stage B: expand +-1 bf16 from v-bit-packed codebook plane (L2-hot)
#pragma unroll
    for (int p = 0; p < 2; ++p) {
      int q = t + 512 * p;
      int r = q >> 3, vv = (q & 7) * 8;
      u32 bits = CbTb[((long)fu * D + d0 + r) * 16 + ((vb + vv) >> 5)];
      int sh = (vb + vv) & 31;
      u16x8 o;
#pragma unroll
      for (int i = 0; i < 8; ++i)
        o[i] = (u16)(0x3F80u | (((bits >> (sh + i)) & 1u) << 15));  // +-1.0 bf16
      *(u16x8*)&lB[r * 88 + vv] = o;
    }
    __syncthreads();
#pragma unroll
    for (int ks2 = 0; ks2 < 2; ++ks2) {
      const int kb = ks2 * 32 + quad * 8;
      bf16x8 bf0 = *(const bf16x8*)&lB[(wd * 32 + lm) * 88 + kb];
      bf16x8 bf1 = *(const bf16x8*)&lB[(wd * 32 + 16 + lm) * 88 + kb];
#pragma unroll
      for (int m = 0; m < 2; ++m) {
        const int mt = wm * 2 + m;
        bf16x8 ah = *(const bf16x8*)&lAh[(mt * 16 + lm) * 88 + kb];
        bf16x8 al = *(const bf16x8*)&lAl[(mt * 16 + lm) * 88 + kb];
        accH[m][0] = __builtin_amdgcn_mfma_f32_16x16x32_bf16(ah, bf0, accH[m][0], 0, 0, 0);
        accH[m][1] = __builtin_amdgcn_mfma_f32_16x16x32_bf16(ah, bf1, accH[m][1], 0, 0, 0);
        accL[m][0] = __builtin_amdgcn_mfma_f32_16x16x32_bf16(al, bf0, accL[m][0], 0, 0, 0);
        accL[m][1] = __builtin_amdgcn_mfma_f32_16x16x32_bf16(al, bf1, accL[m][1], 0, 0, 0);
      }
    }
  }
  // epilogue: ballot bit (quad*16+lm) of pass nt -> bit (nt*16+lm) of word W
  // for b = (wm*2+m)*16 + quad*4 + r. Warps write distinct b rows.
  const int W = dt * 4 + wd;
  bool anyd = false, zf = false;
#pragma unroll
  for (int m = 0; m < 2; ++m)
#pragma unroll
    for (int r = 0; r < 4; ++r) {
      float v0 = 256.f * accH[m][0][r] + accL[m][0][r];
      float v1 = 256.f * accH[m][1][r] + accL[m][1][r];
      u64 s0 = __ballot(v0 < 0.f);
      u64 s1 = __ballot(v1 < 0.f);
      u64 z0 = __ballot(v0 == 0.f);
      u64 z1 = __ballot(v1 == 0.f);
      zf |= ((z0 | z1) != 0ull);
      if (lm == 0) {
        u32 ws = (u32)((s0 >> (quad * 16)) & 0xffffull) |
                 (((u32)((s1 >> (quad * 16)) & 0xffffull)) << 16);
        u32 wz = (u32)((z0 >> (quad * 16)) & 0xffffull) |
                 (((u32)((z1 >> (quad * 16)) & 0xffffull)) << 16);
        int b = (wm * 2 + m) * 16 + quad * 4 + r;
        int idx = (b * F + fu) * DW + W;
        anyd |= (esIn[idx] != ws) || (ezIn[idx] != wz);
        esOut[idx] = ws;
        ezOut[idx] = wz;
      }
    }
  if (__any(anyd) && lane == 0) atomicOr(&flags[iter], 1);
  if (zf && lane == 0) atomicOr(&flags[16], 1);
}

// ---------------------------------------------------------------------------
// final: argmax over V per (b,f) (first-max tie-break) + iteration count
// ---------------------------------------------------------------------------
__global__ __launch_bounds__(64) void k_out(const int* __restrict__ sim,
                                            const int* __restrict__ flags,
                                            int* __restrict__ out) {
  int bid = blockIdx.x;  // 0..191
  int b = bid / F, f = bid % F;
  int lane = threadIdx.x;
  const int* row = sim + (f * B + b) * V;
  int best = -2147483647;
  int bidx = 0;
#pragma unroll
  for (int i = 0; i < V / 64; ++i) {
    int v = lane + 64 * i;  // ascending within lane -> strict > keeps first max
    int x = row[v];
    if (x > best) { best = x; bidx = v; }
  }
  for (int off = 32; off; off >>= 1) {
    int ov = __shfl_down(best, off, 64);
    int oi = __shfl_down(bidx, off, 64);
    if (ov > best || (ov == best && oi < bidx)) { best = ov; bidx = oi; }
  }
  if (lane == 0) out[b * F + f] = bidx;
  if (bid == 0 && lane == 0) {
    int first0 = ITERS;
    for (int i = 0; i < ITERS; ++i) {
      if (flags[i] == 0) { first0 = i; break; }
    }
    int cnt = (first0 < ITERS) ? (first0 + 1) : ITERS;
    out[B * F] = cnt - 1;
  }
}

// ---------------------------------------------------------------------------
extern "C" void kernel_launch(void* const* d_in, const int* in_sizes, int n_in,
                              void* d_out, int out_size, void* d_ws, size_t ws_size,
                              hipStream_t stream) {
  const float* inputs    = (const float*)d_in[0];  // (B, D)
  const float* init_est  = (const float*)d_in[1];  // (B, F, D)
  const float* codebooks = (const float*)d_in[2];  // (F, V, D)

  char* w = (char*)d_ws;
  size_t o = 0;
  auto alloc = [&](size_t bytes) -> void* {
    void* p = w + o;
    o = (o + bytes + 255) & ~(size_t)255;
    return p;
  };
  u32* Cbits   = (u32*)alloc((size_t)F * 64 * 512 * 4 * 4);  // d-bit-packed
  u32* CbTb    = (u32*)alloc((size_t)F * D * 16 * 4);        // v-bit-packed
  u32* in_bits = (u32*)alloc((size_t)B * DW * 4);
  u32* es0     = (u32*)alloc((size_t)B * F * DW * 4);
  u32* ez0     = (u32*)alloc((size_t)B * F * DW * 4);
  u32* es1     = (u32*)alloc((size_t)B * F * DW * 4);
  u32* ez1     = (u32*)alloc((size_t)B * F * DW * 4);
  int* sim     = (int*)alloc((size_t)F * B * V * 4);
  int* flags   = (int*)alloc(128);

  k_init_tr<<<dim3(128, 8, 3), 256, 0, stream>>>(codebooks, Cbits, CbTb, flags);
  k_init_pack<<<1024, 256, 0, stream>>>(inputs, init_est, in_bits, es0, ez0, flags);

  for (int j = 0; j < ITERS; ++j) {
    k_sim<<<192, 512, 0, stream>>>(Cbits, in_bits, es0, ez0, es1, ez1, sim, flags, j);
    k_upd<<<192, 512, 0, stream>>>(sim, CbTb, es0, ez0, es1, ez1, flags, j);
  }
  k_sim<<<192, 512, 0, stream>>>(Cbits, in_bits, es0, ez0, es1, ez1, sim, flags, ITERS);
  k_out<<<B * F, 64, 0, stream>>>(sim, flags, (int*)d_out);
}